// Round 5
// baseline (245.898 us; speedup 1.0000x reference)
//
#include <hip/hip_runtime.h>
#include <hip/hip_fp16.h>

// ChebyshevKAN: y[b,o] = sum_{i,j} U_j(tanh(x[b,i])) * C[i,o,j]
//   B=65536, I=512, O=32, degree 8 (j=0..8).
// Round 5: MEASUREMENT ROUND. Algorithm identical to round 4 (LDS-shared B,
// 2-chunk barrier periods, global_load_lds staging, register x prefetch),
// but the main body runs TWICE per dispatch (runtime rep_off=0 keeps the
// passes identical yet opaque to the compiler). Purpose:
//   (a) T_main = dur(r5) - dur(r4) exactly;
//   (b) the doubled dispatch (~2T > 78us) enters rocprof top-5, finally
//       exposing FETCH/VALUBusy/MfmaUtil/Occupancy/VGPR for the hot kernel.

typedef _Float16 half8 __attribute__((ext_vector_type(8)));
typedef __fp16  fp16x2 __attribute__((ext_vector_type(2)));   // cvt_pkrtz return type
typedef float float4v __attribute__((ext_vector_type(4)));

#define N_I 512
#define N_O 32
#define N_PERIODS 8
#define STEPS 8
#define PERIOD_F16 16384      // two 32-i chunks of packed B
#define PERIOD_BYTES 32768

// ---- prep: pack B to fragment order (blocks 0..511) + bias (block 512) ----
// B_sw flat index: ((s_glob*2 + t)*64 + L)*8 + jj
//   s_glob = ci*8 + (j-1); k_local(ii) = (L>>4)*8 + jj; i = ci*32 + ii
//   o = t*16 + (L&15)     [layout verified: rounds 1/3/4 passed]
__global__ void prep(const float* __restrict__ coeffs, _Float16* __restrict__ bsw,
                     float* __restrict__ bias) {
    if (blockIdx.x == 512) {
        int o = threadIdx.x >> 3, p = threadIdx.x & 7;
        float s = 0.f;
        for (int i = p; i < N_I; i += 8) s += coeffs[(i * 32 + o) * 9];
        for (int off = 4; off; off >>= 1) s += __shfl_down(s, off, 8);
        if (p == 0) bias[o] = s;
        return;
    }
    int id = blockIdx.x * 256 + threadIdx.x;
    int jj = id & 7;
    int L  = (id >> 3) & 63;
    int t  = (id >> 9) & 1;
    int s  = id >> 10;
    int ci = s >> 3, sl = s & 7;
    int j  = sl + 1;
    int ii = ((L >> 4) << 3) + jj;
    int i  = ci * 32 + ii;
    int o  = t * 16 + (L & 15);
    bsw[id] = (_Float16)coeffs[(i * 32 + o) * 9 + j];
}

__device__ __forceinline__ float fast_tanh(float v) {
    float e = __expf(2.0f * v);
    return __builtin_fmaf(-2.0f, __builtin_amdgcn_rcpf(e + 1.0f), 1.0f);
}

__device__ __forceinline__ half8 pack8(const float* u) {
    union { fp16x2 h[4]; half8 v; } r;
    r.h[0] = __builtin_amdgcn_cvt_pkrtz(u[0], u[1]);
    r.h[1] = __builtin_amdgcn_cvt_pkrtz(u[2], u[3]);
    r.h[2] = __builtin_amdgcn_cvt_pkrtz(u[4], u[5]);
    r.h[3] = __builtin_amdgcn_cvt_pkrtz(u[6], u[7]);
    return r.v;
}

__global__ __launch_bounds__(256, 2) void cheby_main(
        const float* __restrict__ x, const _Float16* __restrict__ bsw,
        const float* __restrict__ bias, float* __restrict__ y, int rep_off) {
    __shared__ __align__(16) _Float16 bl[2][PERIOD_F16];   // 2 x 32 KB double buffer

    const int tid = threadIdx.x;
    const int wv  = tid >> 6;
    const int L   = tid & 63;
    const int q   = L >> 4;
    const int mr  = L & 15;
    const int m0  = blockIdx.x * 128 + wv * 32;
    const char* gB = (const char*)bsw;

#pragma unroll 1
    for (int rep = 0; rep < 2; ++rep) {
        // rep_off == 0 at runtime: pass 1 repeats pass 0 exactly, but the
        // compiler must keep both (offsets are runtime values).
        const float* xr0 = x + (size_t)(m0 + mr) * N_I + q * 8 + (size_t)rep * rep_off;
        const float* xr1 = xr0 + 16 * N_I;

        float4v acc[2][2];
#pragma unroll
        for (int a = 0; a < 2; ++a)
#pragma unroll
            for (int b = 0; b < 2; ++b)
#pragma unroll
                for (int e = 0; e < 4; ++e) acc[a][b][e] = 0.f;

        auto stage = [&](int p, int buf) {
            const char* gsrc = gB + (size_t)p * PERIOD_BYTES + wv * 8192 + L * 16;
            char* lds = (char*)&bl[buf][0] + wv * 8192;
#pragma unroll
            for (int it = 0; it < 8; ++it) {
                __builtin_amdgcn_global_load_lds(
                    (const __attribute__((address_space(1))) void*)(gsrc + it * 1024),
                    (__attribute__((address_space(3))) void*)(lds + it * 1024),
                    16, 0, 0);
            }
        };

        auto loadx = [&](int p, float4v* v) {
#pragma unroll
            for (int c = 0; c < 2; ++c) {
                const int o = (p * 2 + c) * 32;
                v[c * 4 + 0] = *(const float4v*)(xr0 + o);
                v[c * 4 + 1] = *(const float4v*)(xr0 + o + 4);
                v[c * 4 + 2] = *(const float4v*)(xr1 + o);
                v[c * 4 + 3] = *(const float4v*)(xr1 + o + 4);
            }
        };

        auto chunk = [&](const _Float16* bb, float4v xa, float4v xb,
                         float4v xc, float4v xd) {
            float w0[8], w1[8], up0[8], uc0[8], up1[8], uc1[8];
#pragma unroll
            for (int e = 0; e < 4; ++e) {
                w0[e]     = 2.0f * fast_tanh(xa[e]);
                w0[e + 4] = 2.0f * fast_tanh(xb[e]);
                w1[e]     = 2.0f * fast_tanh(xc[e]);
                w1[e + 4] = 2.0f * fast_tanh(xd[e]);
            }
#pragma unroll
            for (int e = 0; e < 8; ++e) {          // U_0 = 1, U_1 = 2*xt
                up0[e] = 1.0f; uc0[e] = w0[e];
                up1[e] = 1.0f; uc1[e] = w1[e];
            }
#pragma unroll
            for (int s = 0; s < STEPS; ++s) {      // j = s+1
                const half8 a0 = pack8(uc0);
                const half8 a1 = pack8(uc1);
                const half8 b0 = *(const half8*)(bb + (s * 2 + 0) * 512 + L * 8);
                const half8 b1 = *(const half8*)(bb + (s * 2 + 1) * 512 + L * 8);
                acc[0][0] = __builtin_amdgcn_mfma_f32_16x16x32_f16(a0, b0, acc[0][0], 0, 0, 0);
                acc[0][1] = __builtin_amdgcn_mfma_f32_16x16x32_f16(a0, b1, acc[0][1], 0, 0, 0);
                acc[1][0] = __builtin_amdgcn_mfma_f32_16x16x32_f16(a1, b0, acc[1][0], 0, 0, 0);
                acc[1][1] = __builtin_amdgcn_mfma_f32_16x16x32_f16(a1, b1, acc[1][1], 0, 0, 0);
#pragma unroll
                for (int e = 0; e < 8; ++e) {      // U_{n+1} = w*U_n - U_{n-1}
                    float n0 = __builtin_fmaf(w0[e], uc0[e], -up0[e]);
                    float n1 = __builtin_fmaf(w1[e], uc1[e], -up1[e]);
                    up0[e] = uc0[e]; uc0[e] = n0;
                    up1[e] = uc1[e]; uc1[e] = n1;
                }
            }
        };

        float4v cur[8], nxt[8];
        stage(0, 0);
        loadx(0, cur);
        __syncthreads();                            // staging drained

        for (int p = 0; p < N_PERIODS; ++p) {
            const int buf = p & 1;
            if (p < N_PERIODS - 1) {
                stage(p + 1, buf ^ 1);
                loadx(p + 1, nxt);
            }
            chunk(&bl[buf][0],    cur[0], cur[1], cur[2], cur[3]);
            chunk(&bl[buf][8192], cur[4], cur[5], cur[6], cur[7]);
#pragma unroll
            for (int k = 0; k < 8; ++k) cur[k] = nxt[k];
            __syncthreads();
        }

        // epilogue: C/D layout row = q*4 + e, col = mr (verified)
        const float b_n0 = bias[mr];
        const float b_n1 = bias[16 + mr];
        float* yr = y + (size_t)rep * rep_off;
#pragma unroll
        for (int mt = 0; mt < 2; ++mt) {
#pragma unroll
            for (int e = 0; e < 4; ++e) {
                const int r = m0 + mt * 16 + q * 4 + e;
                yr[(size_t)r * N_O + mr]      = acc[mt][0][e] + b_n0;
                yr[(size_t)r * N_O + 16 + mr] = acc[mt][1][e] + b_n1;
            }
        }
        __syncthreads();                            // bl[] safe to re-stage in next rep
    }
}

extern "C" void kernel_launch(void* const* d_in, const int* in_sizes, int n_in,
                              void* d_out, int out_size, void* d_ws, size_t ws_size,
                              hipStream_t stream) {
    const float* x      = (const float*)d_in[0];
    const float* coeffs = (const float*)d_in[1];
    float* yout = (float*)d_out;

    _Float16* bsw = (_Float16*)d_ws;                               // 131072 f16 = 256KB
    float* bias   = (float*)((char*)d_ws + 131072 * sizeof(_Float16));

    prep<<<513, 256, 0, stream>>>(coeffs, bsw, bias);
    cheby_main<<<512, 256, 0, stream>>>(x, bsw, bias, yout, 0);
}

// Round 6
// 214.393 us; speedup vs baseline: 1.1470x; 1.1470x over previous
//
#include <hip/hip_runtime.h>
#include <hip/hip_fp16.h>

// ChebyshevKAN: y[b,o] = sum_{i,j} U_j(tanh(x[b,i])) * C[i,o,j]
//   B=65536, I=512, O=32, degree 8 (j=0..8).
// Round 6: VALU diet + deeper pipeline (r5 counters: NOT HBM-bound — 20% peak;
// VALU/issue + exposed latency are the walls).
//   - Chebyshev recurrence in packed f16 (v_pk_fma_f16): uc regs ARE the MFMA
//     A-fragment; no per-step pkrtz repack. tanh stays fp32; w=2*tanh packed
//     once per chunk (w = 2 - 4/(exp(2v)+1), one fewer mul).
//   - per-chunk (16 KB) LDS double buffer (32 KB total), stage AFTER barrier
//     so the vmcnt drain at the next barrier is one full chunk away.
//   - x register-prefetch 2 chunks deep (> 900 cy HBM latency), unroll-2
//     chunk loop -> prefetch slots are SSA, no copies.
// Block 256 = 4 waves; wave = 32 rows x 32 cols; grid 512.

typedef _Float16 half8  __attribute__((ext_vector_type(8)));
typedef _Float16 half2v __attribute__((ext_vector_type(2)));
typedef __fp16   fp16x2 __attribute__((ext_vector_type(2)));   // cvt_pkrtz return type
typedef float    float4v __attribute__((ext_vector_type(4)));

#define N_I 512
#define N_O 32
#define N_CHUNKS 16
#define STEPS 8
#define CHUNK_F16 8192        // one 32-i chunk of packed B, f16 elements
#define CHUNK_BYTES 16384

// ---- prep: pack B to fragment order (blocks 0..511) + bias (block 512) ----
// B_sw flat index: ((s_glob*2 + t)*64 + L)*8 + jj
//   s_glob = ci*8 + (j-1); k_local(ii) = (L>>4)*8 + jj; i = ci*32 + ii
//   o = t*16 + (L&15)     [layout verified: rounds 1/3/4/5 passed]
__global__ void prep(const float* __restrict__ coeffs, _Float16* __restrict__ bsw,
                     float* __restrict__ bias) {
    if (blockIdx.x == 512) {
        int o = threadIdx.x >> 3, p = threadIdx.x & 7;
        float s = 0.f;
        for (int i = p; i < N_I; i += 8) s += coeffs[(i * 32 + o) * 9];
        for (int off = 4; off; off >>= 1) s += __shfl_down(s, off, 8);
        if (p == 0) bias[o] = s;
        return;
    }
    int id = blockIdx.x * 256 + threadIdx.x;
    int jj = id & 7;
    int L  = (id >> 3) & 63;
    int t  = (id >> 9) & 1;
    int s  = id >> 10;
    int ci = s >> 3, sl = s & 7;
    int j  = sl + 1;
    int ii = ((L >> 4) << 3) + jj;
    int i  = ci * 32 + ii;
    int o  = t * 16 + (L & 15);
    bsw[id] = (_Float16)coeffs[(i * 32 + o) * 9 + j];
}

__device__ __forceinline__ float wfun(float v) {
    // 2*tanh(v) = 2 - 4/(exp(2v)+1); exact at +-inf, error << f16 quant.
    float e = __expf(2.0f * v);
    return __builtin_fmaf(-4.0f, __builtin_amdgcn_rcpf(e + 1.0f), 2.0f);
}

__device__ __forceinline__ half2v pkh(float a, float b) {
    union { fp16x2 f; half2v h; } u;
    u.f = __builtin_amdgcn_cvt_pkrtz(a, b);
    return u.h;
}

union H8 { half2v h2[4]; half8 v; };

__global__ __launch_bounds__(256, 2) void cheby_main(
        const float* __restrict__ x, const _Float16* __restrict__ bsw,
        const float* __restrict__ bias, float* __restrict__ y) {
    __shared__ __align__(16) _Float16 bl[2][CHUNK_F16];   // 2 x 16 KB

    const int tid = threadIdx.x;
    const int wv  = tid >> 6;
    const int L   = tid & 63;
    const int q   = L >> 4;
    const int mr  = L & 15;
    const int m0  = blockIdx.x * 128 + wv * 32;
    const float* xr0 = x + (size_t)(m0 + mr) * N_I + q * 8;   // M-tile 0 row
    const float* xr1 = xr0 + 16 * N_I;                        // M-tile 1 row
    const char* gB = (const char*)bsw;

    float4v acc[2][2];
#pragma unroll
    for (int a = 0; a < 2; ++a)
#pragma unroll
        for (int b = 0; b < 2; ++b)
#pragma unroll
            for (int e = 0; e < 4; ++e) acc[a][b][e] = 0.f;

    // stage one 16 KB chunk: 4 wave-iters x 1 KB (wave-uniform LDS base,
    // lanes auto-scatter at L*16; pack order is linear)
    auto stage = [&](int ci, int buf) {
        const char* gsrc = gB + (size_t)ci * CHUNK_BYTES + wv * 1024 + L * 16;
        char* lds = (char*)&bl[buf][0] + wv * 1024;
#pragma unroll
        for (int it = 0; it < 4; ++it) {
            __builtin_amdgcn_global_load_lds(
                (const __attribute__((address_space(1))) void*)(gsrc + it * 4096),
                (__attribute__((address_space(3))) void*)(lds + it * 4096),
                16, 0, 0);
        }
    };

    auto loadx = [&](int ci, float4v* v) {
        const int o = ci * 32;
        v[0] = *(const float4v*)(xr0 + o);
        v[1] = *(const float4v*)(xr0 + o + 4);
        v[2] = *(const float4v*)(xr1 + o);
        v[3] = *(const float4v*)(xr1 + o + 4);
    };

    const half2v one = {(_Float16)1.0f, (_Float16)1.0f};

    // one 32-i chunk: fp32 tanh -> packed f16 recurrence -> 8 K-steps MFMA
    auto chunk = [&](const _Float16* bb, const float4v* xv) {
        float wf0[8], wf1[8];
#pragma unroll
        for (int e = 0; e < 4; ++e) {
            wf0[e]     = wfun(xv[0][e]);
            wf0[e + 4] = wfun(xv[1][e]);
            wf1[e]     = wfun(xv[2][e]);
            wf1[e + 4] = wfun(xv[3][e]);
        }
        half2v w0[4], w1[4], uc0[4], uc1[4], up0[4], up1[4];
#pragma unroll
        for (int h = 0; h < 4; ++h) {
            w0[h] = pkh(wf0[2 * h], wf0[2 * h + 1]);
            w1[h] = pkh(wf1[2 * h], wf1[2 * h + 1]);
            uc0[h] = w0[h]; uc1[h] = w1[h];   // U_1 = 2*tanh = w
            up0[h] = one;   up1[h] = one;     // U_0 = 1 (loop-invariant const)
        }
#pragma unroll
        for (int s = 0; s < STEPS; ++s) {     // j = s+1
            H8 a0, a1;
#pragma unroll
            for (int h = 0; h < 4; ++h) { a0.h2[h] = uc0[h]; a1.h2[h] = uc1[h]; }
            const half8 b0 = *(const half8*)(bb + (s * 2 + 0) * 512 + L * 8);
            const half8 b1 = *(const half8*)(bb + (s * 2 + 1) * 512 + L * 8);
            acc[0][0] = __builtin_amdgcn_mfma_f32_16x16x32_f16(a0.v, b0, acc[0][0], 0, 0, 0);
            acc[0][1] = __builtin_amdgcn_mfma_f32_16x16x32_f16(a0.v, b1, acc[0][1], 0, 0, 0);
            acc[1][0] = __builtin_amdgcn_mfma_f32_16x16x32_f16(a1.v, b0, acc[1][0], 0, 0, 0);
            acc[1][1] = __builtin_amdgcn_mfma_f32_16x16x32_f16(a1.v, b1, acc[1][1], 0, 0, 0);
#pragma unroll
            for (int h = 0; h < 4; ++h) {     // packed f16: U_{n+1} = w*U_n - U_{n-1}
                half2v n0 = w0[h] * uc0[h] - up0[h];
                half2v n1 = w1[h] * uc1[h] - up1[h];
                up0[h] = uc0[h]; uc0[h] = n0;
                up1[h] = uc1[h]; uc1[h] = n1;
            }
        }
    };

    float4v xv[2][4];
    loadx(0, xv[0]);
    loadx(1, xv[1]);
    stage(0, 0);
    __syncthreads();                          // startup drain (once)

#pragma unroll 2
    for (int ci = 0; ci < N_CHUNKS; ++ci) {
        const int buf = ci & 1;
        if (ci + 1 < N_CHUNKS) stage(ci + 1, buf ^ 1);   // issued AFTER barrier
        float4v xcur[4];
#pragma unroll
        for (int k = 0; k < 4; ++k) xcur[k] = xv[buf][k];
        if (ci + 2 < N_CHUNKS) loadx(ci + 2, xv[buf]);   // 2-chunk-deep prefetch
        chunk(&bl[buf][0], xcur);
        __syncthreads();                      // drains stage(ci+1), 1 chunk later
    }

    // epilogue: C/D layout row = q*4 + e, col = mr (verified)
    const float b_n0 = bias[mr];
    const float b_n1 = bias[16 + mr];
#pragma unroll
    for (int mt = 0; mt < 2; ++mt) {
#pragma unroll
        for (int e = 0; e < 4; ++e) {
            const int r = m0 + mt * 16 + q * 4 + e;
            y[(size_t)r * N_O + mr]      = acc[mt][0][e] + b_n0;
            y[(size_t)r * N_O + 16 + mr] = acc[mt][1][e] + b_n1;
        }
    }
}

extern "C" void kernel_launch(void* const* d_in, const int* in_sizes, int n_in,
                              void* d_out, int out_size, void* d_ws, size_t ws_size,
                              hipStream_t stream) {
    const float* x      = (const float*)d_in[0];
    const float* coeffs = (const float*)d_in[1];
    float* yout = (float*)d_out;

    _Float16* bsw = (_Float16*)d_ws;                               // 131072 f16 = 256KB
    float* bias   = (float*)((char*)d_ws + 131072 * sizeof(_Float16));

    prep<<<513, 256, 0, stream>>>(coeffs, bsw, bias);
    cheby_main<<<512, 256, 0, stream>>>(x, bsw, bias, yout);
}